// Round 2
// baseline (1229.457 us; speedup 1.0000x reference)
//
#include <hip/hip_runtime.h>
#include <cstdint>
#include <cstddef>

#define TT 4096   // T = H*W
#define CCH 256   // C

// ---------------- Kernel 1: GroupNorm stats (mean, rstd) per (b, group) ----
// blockIdx.x = b*32+g; the 8 channels of a group are contiguous: 32768 f32.
__global__ __launch_bounds__(256)
void gn_stats(const float* __restrict__ x, float* __restrict__ stats){
  const float4* p = (const float4*)(x + (size_t)blockIdx.x * 8 * TT);
  int tid = threadIdx.x;
  float s = 0.f, sq = 0.f;
  #pragma unroll
  for (int it = 0; it < 32; ++it){
    float4 u = p[it * 256 + tid];
    s  += u.x + u.y + u.z + u.w;
    sq += u.x*u.x + u.y*u.y + u.z*u.z + u.w*u.w;
  }
  #pragma unroll
  for (int off = 32; off >= 1; off >>= 1){
    s  += __shfl_down(s, off);
    sq += __shfl_down(sq, off);
  }
  __shared__ float ls[4], lq[4];
  int w_ = tid >> 6, lane = tid & 63;
  if (lane == 0){ ls[w_] = s; lq[w_] = sq; }
  __syncthreads();
  if (tid == 0){
    float S = ls[0]+ls[1]+ls[2]+ls[3];
    float Q = lq[0]+lq[1]+lq[2]+lq[3];
    float mean = S * (1.f/32768.f);
    float var  = Q * (1.f/32768.f) - mean*mean;
    stats[2*blockIdx.x]   = mean;
    stats[2*blockIdx.x+1] = rsqrtf(var + 1e-5f);
  }
}

// ---------------- Kernel 2: apply GN -> xn (f32) ----------------------------
__global__ __launch_bounds__(256)
void gn_apply(const float* __restrict__ x, const float* __restrict__ gw,
              const float* __restrict__ gb, const float* __restrict__ stats,
              float* __restrict__ xn){
  size_t i4 = ((size_t)blockIdx.x * 256 + threadIdx.x) * 4;
  int bc = (int)(i4 >> 12);          // b*256 + c  (each channel = 4096 elems)
  int c = bc & 255;
  int b = bc >> 8;
  int sg = (b << 5) | (c >> 3);
  float mean = stats[2*sg], rstd = stats[2*sg+1];
  float scale = gw[c] * rstd;
  float shift = gb[c] - mean * scale;
  float4 u = *(const float4*)(x + i4);
  float4 r;
  r.x = u.x*scale + shift;
  r.y = u.y*scale + shift;
  r.z = u.z*scale + shift;
  r.w = u.w*scale + shift;
  *(float4*)(xn + i4) = r;
}

// ---------------- Kernel 3: QKV GEMM  qkv[b,o,t] = W[o,:]·xn[b,:,t] + bias --
// grid (T/64, 768/64, B), 64x64 tile, 4x4 micro-tile per thread, K-step 16.
__global__ __launch_bounds__(256)
void qkv_gemm(const float* __restrict__ w, const float* __restrict__ bias,
              const float* __restrict__ xn, float* __restrict__ out){
  __shared__ float wt[16][68];   // wt[k][o]  (transposed W tile)
  __shared__ float xt[16][68];   // xt[k][t]
  int b = blockIdx.z;
  int o0 = blockIdx.y << 6;
  int t0 = blockIdx.x << 6;
  int tid = threadIdx.x;
  int tr = tid >> 4, ts = tid & 15;
  const float* xb = xn + (size_t)b * CCH * TT;
  float acc[4][4] = {};
  for (int k0 = 0; k0 < 256; k0 += 16){
    __syncthreads();
    { // W tile: 64 rows x 16 k -> transposed into LDS
      int ol = tid >> 2, kq = (tid & 3) << 2;
      float4 u = *(const float4*)(w + (size_t)(o0 + ol) * 256 + k0 + kq);
      wt[kq+0][ol] = u.x;
      wt[kq+1][ol] = u.y;
      wt[kq+2][ol] = u.z;
      wt[kq+3][ol] = u.w;
    }
    { // X tile: 16 rows x 64 t
      int kl = tid >> 4, j4 = (tid & 15) << 2;
      float4 u = *(const float4*)(xb + (size_t)(k0 + kl) * TT + t0 + j4);
      xt[kl][j4+0] = u.x;
      xt[kl][j4+1] = u.y;
      xt[kl][j4+2] = u.z;
      xt[kl][j4+3] = u.w;
    }
    __syncthreads();
    #pragma unroll
    for (int k = 0; k < 16; ++k){
      float4 a4 = *(const float4*)&wt[k][tr<<2];
      float4 b4 = *(const float4*)&xt[k][ts<<2];
      float av[4] = {a4.x,a4.y,a4.z,a4.w};
      float bv[4] = {b4.x,b4.y,b4.z,b4.w};
      #pragma unroll
      for (int i=0;i<4;++i)
        #pragma unroll
        for (int j=0;j<4;++j)
          acc[i][j] = fmaf(av[i], bv[j], acc[i][j]);
    }
  }
  #pragma unroll
  for (int i=0;i<4;++i){
    int o = o0 + (tr<<2) + i;
    float bs = bias[o];
    size_t base = ((size_t)b * 768 + o) * TT + t0 + (ts<<2);
    float4 r;
    r.x = acc[i][0]+bs; r.y = acc[i][1]+bs;
    r.z = acc[i][2]+bs; r.w = acc[i][3]+bs;
    *(float4*)(out + base) = r;
  }
}

// ---------------- Kernel 4: flash attention -------------------------------
// one block = (b, h, 64-query tile). q,k,v are [64ch][T] slices of qkv ws.
// S[t,s] = 0.125 * sum_c q[c,t] k[c,s]; online softmax; O[t,c] = sum_s P V.
__global__ __launch_bounds__(256)
void attn(const float* __restrict__ qkv, float* __restrict__ a){
  __shared__ float q_lds[64][68];    // q[c][t_local]      (later reused for O)
  __shared__ float kp_lds[64][68];   // K: k[c][s_local];  then P: p[s][t_local]
  __shared__ float vt_lds[64][68];   // V transposed: v[s_local][c]
  int tid = threadIdx.x;
  int qt = blockIdx.x & 63, bh = blockIdx.x >> 6;
  int b = bh >> 2, h = bh & 3;
  int t0 = qt << 6;
  const float* qb = qkv + ((size_t)b*768 + (h<<6)) * TT;
  const float* kb = qb + (size_t)256 * TT;
  const float* vb = qb + (size_t)512 * TT;
  int tr = tid >> 4, ts = tid & 15;
  int r0 = tr << 2, c0 = ts << 2;

  #pragma unroll
  for (int it = 0; it < 4; ++it){
    int fid = (it << 8) + tid;
    int cc = fid >> 4, j4 = (fid & 15) << 2;
    float4 u = *(const float4*)(qb + (size_t)cc * TT + t0 + j4);
    q_lds[cc][j4+0] = u.x;
    q_lds[cc][j4+1] = u.y;
    q_lds[cc][j4+2] = u.z;
    q_lds[cc][j4+3] = u.w;
  }

  float m_i[4], l_i[4], o_acc[4][4] = {};
  #pragma unroll
  for (int i=0;i<4;++i){ m_i[i] = -1e30f; l_i[i] = 0.f; }

  for (int st = 0; st < 64; ++st){
    int s0g = st << 6;
    __syncthreads();   // prev O-phase done before overwriting K/V
    #pragma unroll
    for (int it = 0; it < 4; ++it){
      int fid = (it << 8) + tid;
      int cc = fid >> 4, j4 = (fid & 15) << 2;
      float4 u = *(const float4*)(kb + (size_t)cc * TT + s0g + j4);
      kp_lds[cc][j4+0] = u.x;
      kp_lds[cc][j4+1] = u.y;
      kp_lds[cc][j4+2] = u.z;
      kp_lds[cc][j4+3] = u.w;
      float4 v = *(const float4*)(vb + (size_t)cc * TT + s0g + j4);
      vt_lds[j4+0][cc] = v.x;
      vt_lds[j4+1][cc] = v.y;
      vt_lds[j4+2][cc] = v.z;
      vt_lds[j4+3][cc] = v.w;
    }
    __syncthreads();
    // S = Q^T K  (4x4 micro-tile)
    float sacc[4][4] = {};
    #pragma unroll 8
    for (int cc = 0; cc < 64; ++cc){
      float4 qa = *(const float4*)&q_lds[cc][r0];
      float4 ka = *(const float4*)&kp_lds[cc][c0];
      float qv[4]={qa.x,qa.y,qa.z,qa.w}, kv[4]={ka.x,ka.y,ka.z,ka.w};
      #pragma unroll
      for (int i=0;i<4;++i)
        #pragma unroll
        for (int j=0;j<4;++j)
          sacc[i][j] = fmaf(qv[i], kv[j], sacc[i][j]);
    }
    #pragma unroll
    for (int i=0;i<4;++i)
      #pragma unroll
      for (int j=0;j<4;++j) sacc[i][j] *= 0.125f;
    // online softmax, rows owned by 16 lanes (ts): shfl_xor reductions
    float p[4][4], alpha[4];
    #pragma unroll
    for (int i=0;i<4;++i){
      float rm = fmaxf(fmaxf(sacc[i][0],sacc[i][1]), fmaxf(sacc[i][2],sacc[i][3]));
      #pragma unroll
      for (int off=1; off<16; off<<=1) rm = fmaxf(rm, __shfl_xor(rm, off));
      float mnew = fmaxf(m_i[i], rm);
      float rsum = 0.f;
      #pragma unroll
      for (int j=0;j<4;++j){ p[i][j] = __expf(sacc[i][j] - mnew); rsum += p[i][j]; }
      #pragma unroll
      for (int off=1; off<16; off<<=1) rsum += __shfl_xor(rsum, off);
      alpha[i] = __expf(m_i[i] - mnew);
      l_i[i] = l_i[i]*alpha[i] + rsum;
      m_i[i] = mnew;
    }
    #pragma unroll
    for (int i=0;i<4;++i)
      #pragma unroll
      for (int j=0;j<4;++j) o_acc[i][j] *= alpha[i];
    __syncthreads();   // everyone done reading K tile
    #pragma unroll
    for (int j=0;j<4;++j){   // P -> LDS, layout p[s][t_local]
      float4 pc; pc.x = p[0][j]; pc.y = p[1][j]; pc.z = p[2][j]; pc.w = p[3][j];
      *(float4*)&kp_lds[c0 + j][r0] = pc;
    }
    __syncthreads();
    // O += P * V^T
    #pragma unroll 8
    for (int s = 0; s < 64; ++s){
      float4 pa = *(const float4*)&kp_lds[s][r0];
      float4 va = *(const float4*)&vt_lds[s][c0];
      float pv[4]={pa.x,pa.y,pa.z,pa.w}, vv[4]={va.x,va.y,va.z,va.w};
      #pragma unroll
      for (int i=0;i<4;++i)
        #pragma unroll
        for (int j=0;j<4;++j)
          o_acc[i][j] = fmaf(pv[i], vv[j], o_acc[i][j]);
    }
  }
  // epilogue: normalize, round-trip via LDS for coalesced store
  __syncthreads();
  float inv[4];
  #pragma unroll
  for (int i=0;i<4;++i) inv[i] = 1.f / l_i[i];
  #pragma unroll
  for (int j=0;j<4;++j){
    float4 oc;
    oc.x = o_acc[0][j]*inv[0]; oc.y = o_acc[1][j]*inv[1];
    oc.z = o_acc[2][j]*inv[2]; oc.w = o_acc[3][j]*inv[3];
    *(float4*)&q_lds[c0 + j][r0] = oc;   // o[c][t_local]
  }
  __syncthreads();
  float* ab = a + ((size_t)b*256 + (h<<6)) * TT;
  #pragma unroll
  for (int it = 0; it < 4; ++it){
    int fid = (it << 8) + tid;
    int cc = fid >> 4, j4 = (fid & 15) << 2;
    float4 o4 = *(const float4*)&q_lds[cc][j4];
    *(float4*)(ab + (size_t)cc * TT + t0 + j4) = o4;
  }
}

// ---------------- Kernel 5: proj GEMM + bias + residual -> out --------------
__global__ __launch_bounds__(256)
void proj_res(const float* __restrict__ w, const float* __restrict__ bias,
              const float* __restrict__ a, const float* __restrict__ x,
              float* __restrict__ out){
  __shared__ float wt[16][68];
  __shared__ float xt[16][68];
  int b = blockIdx.z;
  int o0 = blockIdx.y << 6;
  int t0 = blockIdx.x << 6;
  int tid = threadIdx.x;
  int tr = tid >> 4, ts = tid & 15;
  const float* xb = a + (size_t)b * CCH * TT;
  float acc[4][4] = {};
  for (int k0 = 0; k0 < 256; k0 += 16){
    __syncthreads();
    {
      int ol = tid >> 2, kq = (tid & 3) << 2;
      float4 u = *(const float4*)(w + (size_t)(o0 + ol) * 256 + k0 + kq);
      wt[kq+0][ol] = u.x;
      wt[kq+1][ol] = u.y;
      wt[kq+2][ol] = u.z;
      wt[kq+3][ol] = u.w;
    }
    {
      int kl = tid >> 4, j4 = (tid & 15) << 2;
      float4 u = *(const float4*)(xb + (size_t)(k0 + kl) * TT + t0 + j4);
      xt[kl][j4+0] = u.x;
      xt[kl][j4+1] = u.y;
      xt[kl][j4+2] = u.z;
      xt[kl][j4+3] = u.w;
    }
    __syncthreads();
    #pragma unroll
    for (int k = 0; k < 16; ++k){
      float4 a4 = *(const float4*)&wt[k][tr<<2];
      float4 b4 = *(const float4*)&xt[k][ts<<2];
      float av[4] = {a4.x,a4.y,a4.z,a4.w};
      float bv[4] = {b4.x,b4.y,b4.z,b4.w};
      #pragma unroll
      for (int i=0;i<4;++i)
        #pragma unroll
        for (int j=0;j<4;++j)
          acc[i][j] = fmaf(av[i], bv[j], acc[i][j]);
    }
  }
  #pragma unroll
  for (int i=0;i<4;++i){
    int o = o0 + (tr<<2) + i;
    float bs = bias[o];
    size_t base = ((size_t)b * CCH + o) * TT + t0 + (ts<<2);
    float4 xr = *(const float4*)(x + base);
    float4 r;
    r.x = acc[i][0]+bs+xr.x;
    r.y = acc[i][1]+bs+xr.y;
    r.z = acc[i][2]+bs+xr.z;
    r.w = acc[i][3]+bs+xr.w;
    *(float4*)(out + base) = r;
  }
}

extern "C" void kernel_launch(void* const* d_in, const int* in_sizes, int n_in,
                              void* d_out, int out_size, void* d_ws, size_t ws_size,
                              hipStream_t stream){
  const float* x      = (const float*)d_in[0];
  const float* gn_w   = (const float*)d_in[1];
  const float* gn_b   = (const float*)d_in[2];
  const float* qkv_w  = (const float*)d_in[3];
  const float* qkv_b  = (const float*)d_in[4];
  const float* proj_w = (const float*)d_in[5];
  const float* proj_b = (const float*)d_in[6];
  float* out = (float*)d_out;

  // workspace layout (f32): stats(256) | xn (16.8MB) | qkv (50.3MB) | attn (16.8MB)
  float* stats = (float*)d_ws;
  float* xn    = stats + 256;
  float* qkvb  = xn   + (size_t)4*256*4096;
  float* attb  = qkvb + (size_t)4*768*4096;
  // total ~84 MB

  gn_stats<<<128, 256, 0, stream>>>(x, stats);
  gn_apply<<<4096, 256, 0, stream>>>(x, gn_w, gn_b, stats, xn);
  qkv_gemm<<<dim3(64, 12, 4), 256, 0, stream>>>(qkv_w, qkv_b, xn, qkvb);
  attn<<<1024, 256, 0, stream>>>(qkvb, attb);
  proj_res<<<dim3(64, 4, 4), 256, 0, stream>>>(proj_w, proj_b, attb, x, out);
}

// Round 3
// 462.816 us; speedup vs baseline: 2.6565x; 2.6565x over previous
//
#include <hip/hip_runtime.h>
#include <cstdint>
#include <cstddef>

#define TT 4096   // T = H*W
#define CCH 256   // C

typedef __attribute__((ext_vector_type(8))) short short8;
typedef __attribute__((ext_vector_type(4))) float f32x4;

__device__ __forceinline__ float bf2f(unsigned int u){
  union { unsigned int i; float f; } v; v.i = u << 16; return v.f;
}
__device__ __forceinline__ unsigned short f2bf(float f){
  unsigned int x = __float_as_uint(f);
  x += 0x7fffu + ((x >> 16) & 1u);   // RNE
  return (unsigned short)(x >> 16);
}

// ---------------- Kernel 1: GroupNorm stats (mean, rstd) per (b, group) ----
__global__ __launch_bounds__(256)
void gn_stats(const float* __restrict__ x, float* __restrict__ stats){
  const float4* p = (const float4*)(x + (size_t)blockIdx.x * 8 * TT);
  int tid = threadIdx.x;
  float s = 0.f, sq = 0.f;
  #pragma unroll
  for (int it = 0; it < 32; ++it){
    float4 u = p[it * 256 + tid];
    s  += u.x + u.y + u.z + u.w;
    sq += u.x*u.x + u.y*u.y + u.z*u.z + u.w*u.w;
  }
  #pragma unroll
  for (int off = 32; off >= 1; off >>= 1){
    s  += __shfl_down(s, off);
    sq += __shfl_down(sq, off);
  }
  __shared__ float ls[4], lq[4];
  int w_ = tid >> 6, lane = tid & 63;
  if (lane == 0){ ls[w_] = s; lq[w_] = sq; }
  __syncthreads();
  if (tid == 0){
    float S = ls[0]+ls[1]+ls[2]+ls[3];
    float Q = lq[0]+lq[1]+lq[2]+lq[3];
    float mean = S * (1.f/32768.f);
    float var  = Q * (1.f/32768.f) - mean*mean;
    stats[2*blockIdx.x]   = mean;
    stats[2*blockIdx.x+1] = rsqrtf(var + 1e-5f);
  }
}

// ---------------- Kernel 2: apply GN -> xn (f32) ----------------------------
__global__ __launch_bounds__(256)
void gn_apply(const float* __restrict__ x, const float* __restrict__ gw,
              const float* __restrict__ gb, const float* __restrict__ stats,
              float* __restrict__ xn){
  size_t i4 = ((size_t)blockIdx.x * 256 + threadIdx.x) * 4;
  int bc = (int)(i4 >> 12);
  int c = bc & 255;
  int b = bc >> 8;
  int sg = (b << 5) | (c >> 3);
  float mean = stats[2*sg], rstd = stats[2*sg+1];
  float scale = gw[c] * rstd;
  float shift = gb[c] - mean * scale;
  float4 u = *(const float4*)(x + i4);
  float4 r;
  r.x = u.x*scale + shift;
  r.y = u.y*scale + shift;
  r.z = u.z*scale + shift;
  r.w = u.w*scale + shift;
  *(float4*)(xn + i4) = r;
}

// ---------------- Kernel 3: QKV GEMM -> q^T, k^T (bf16 [bh][T][64]), v (bf16 [bh][64][T])
// q pre-scaled by 0.125*log2(e) so attention softmax can use exp2 directly.
__global__ __launch_bounds__(256)
void qkv_gemm(const float* __restrict__ w, const float* __restrict__ bias,
              const float* __restrict__ xn,
              unsigned short* __restrict__ qt, unsigned short* __restrict__ kt,
              unsigned short* __restrict__ vv){
  __shared__ float wt[16][68];
  __shared__ float xt[16][68];
  int b = blockIdx.z;
  int o0 = blockIdx.y << 6;
  int t0 = blockIdx.x << 6;
  int tid = threadIdx.x;
  int tr = tid >> 4, ts = tid & 15;
  const float* xb = xn + (size_t)b * CCH * TT;
  float acc[4][4] = {};
  for (int k0 = 0; k0 < 256; k0 += 16){
    __syncthreads();
    {
      int ol = tid >> 2, kq = (tid & 3) << 2;
      float4 u = *(const float4*)(w + (size_t)(o0 + ol) * 256 + k0 + kq);
      wt[kq+0][ol] = u.x; wt[kq+1][ol] = u.y;
      wt[kq+2][ol] = u.z; wt[kq+3][ol] = u.w;
    }
    {
      int kl = tid >> 4, j4 = (tid & 15) << 2;
      float4 u = *(const float4*)(xb + (size_t)(k0 + kl) * TT + t0 + j4);
      xt[kl][j4+0] = u.x; xt[kl][j4+1] = u.y;
      xt[kl][j4+2] = u.z; xt[kl][j4+3] = u.w;
    }
    __syncthreads();
    #pragma unroll
    for (int k = 0; k < 16; ++k){
      float4 a4 = *(const float4*)&wt[k][tr<<2];
      float4 b4 = *(const float4*)&xt[k][ts<<2];
      float av[4] = {a4.x,a4.y,a4.z,a4.w};
      float bv[4] = {b4.x,b4.y,b4.z,b4.w};
      #pragma unroll
      for (int i=0;i<4;++i)
        #pragma unroll
        for (int j=0;j<4;++j)
          acc[i][j] = fmaf(av[i], bv[j], acc[i][j]);
    }
  }
  float bs[4];
  #pragma unroll
  for (int i=0;i<4;++i) bs[i] = bias[o0 + (tr<<2) + i];
  int sec = blockIdx.y >> 2;        // 0=q,1=k,2=v (o0 64-aligned within section)
  int h = blockIdx.y & 3;
  int bh = (b << 2) | h;
  if (sec == 0){
    const float qsc = 0.125f * 1.44269504f;
    #pragma unroll
    for (int j=0;j<4;++j){
      int t = t0 + (ts<<2) + j;
      ushort4 r;
      r.x = f2bf((acc[0][j]+bs[0])*qsc); r.y = f2bf((acc[1][j]+bs[1])*qsc);
      r.z = f2bf((acc[2][j]+bs[2])*qsc); r.w = f2bf((acc[3][j]+bs[3])*qsc);
      *(ushort4*)(qt + ((size_t)bh*TT + t)*64 + (tr<<2)) = r;
    }
  } else if (sec == 1){
    #pragma unroll
    for (int j=0;j<4;++j){
      int t = t0 + (ts<<2) + j;
      ushort4 r;
      r.x = f2bf(acc[0][j]+bs[0]); r.y = f2bf(acc[1][j]+bs[1]);
      r.z = f2bf(acc[2][j]+bs[2]); r.w = f2bf(acc[3][j]+bs[3]);
      *(ushort4*)(kt + ((size_t)bh*TT + t)*64 + (tr<<2)) = r;
    }
  } else {
    #pragma unroll
    for (int i=0;i<4;++i){
      int c = (tr<<2) + i;
      ushort4 r;
      r.x = f2bf(acc[i][0]+bs[i]); r.y = f2bf(acc[i][1]+bs[i]);
      r.z = f2bf(acc[i][2]+bs[i]); r.w = f2bf(acc[i][3]+bs[i]);
      *(ushort4*)(vv + ((size_t)bh*64 + c)*TT + t0 + (ts<<2)) = r;
    }
  }
}

// ---------------- Kernel 4: flash attention, bf16 MFMA ----------------------
// block = (bh, 64-query tile); 4 waves, each owns a 16-query strip.
// S in log2 domain (q pre-scaled); C/D layout col=lane&15,row=quad*4+reg;
// A layout A[m=lane&15][k=quad*8+j]; B layout B[k=quad*8+j][n=lane&15].
__global__ __launch_bounds__(256)
void attn_mfma(const unsigned short* __restrict__ qt,
               const unsigned short* __restrict__ kt,
               const unsigned short* __restrict__ vv,
               unsigned short* __restrict__ a){
  __shared__ __align__(16) unsigned short q_lds[64][72];  // Qt[t][c]; reused for O[c][t]
  __shared__ __align__(16) unsigned short k_lds[64][72];  // Kt[s][c]
  __shared__ __align__(16) unsigned short v_lds[64][72];  // V[c][s]
  __shared__ __align__(16) unsigned short p_lds[64][72];  // P[t][s]

  int tid = threadIdx.x;
  int w = tid >> 6, lane = tid & 63;
  int quad = lane >> 4, l15 = lane & 15;
  int qtile = blockIdx.x & 63, bh = blockIdx.x >> 6;
  int t0 = qtile << 6;
  const unsigned short* qg = qt + ((size_t)bh*TT + t0)*64;
  const unsigned short* kg = kt + (size_t)bh*TT*64;
  const unsigned short* vg = vv + (size_t)bh*64*TT;

  #pragma unroll
  for (int pass = 0; pass < 2; ++pass){
    int chunk = (pass<<8) + tid;            // 512 chunks of 16B
    int row = chunk >> 3, c8 = (chunk & 7) << 3;
    *(uint4*)&q_lds[row][c8] = *(const uint4*)(qg + row*64 + c8);
  }
  __syncthreads();
  short8 qa0 = *(const short8*)&q_lds[(w<<4)+l15][quad<<3];
  short8 qa1 = *(const short8*)&q_lds[(w<<4)+l15][32+(quad<<3)];

  f32x4 o_acc[4];
  #pragma unroll
  for (int nt=0;nt<4;++nt) o_acc[nt] = (f32x4){0.f,0.f,0.f,0.f};
  float m_r[4], l_r[4];
  #pragma unroll
  for (int r=0;r<4;++r){ m_r[r] = -1e30f; l_r[r] = 0.f; }

  for (int st = 0; st < 64; ++st){
    int s0 = st << 6;
    __syncthreads();   // prior PV reads of k/v done
    #pragma unroll
    for (int pass = 0; pass < 2; ++pass){
      int chunk = (pass<<8) + tid;
      int row = chunk >> 3, c8 = (chunk & 7) << 3;
      *(uint4*)&k_lds[row][c8] = *(const uint4*)(kg + (size_t)(s0+row)*64 + c8);
      *(uint4*)&v_lds[row][c8] = *(const uint4*)(vg + (size_t)row*TT + s0 + c8);
    }
    __syncthreads();
    // S strip: 4 col-tiles x (K=64 via 2 mfma)
    f32x4 sf[4];
    #pragma unroll
    for (int nt=0;nt<4;++nt){
      short8 kb0 = *(const short8*)&k_lds[(nt<<4)+l15][quad<<3];
      short8 kb1 = *(const short8*)&k_lds[(nt<<4)+l15][32+(quad<<3)];
      f32x4 z = (f32x4){0.f,0.f,0.f,0.f};
      z = __builtin_amdgcn_mfma_f32_16x16x32_bf16(qa0, kb0, z, 0, 0, 0);
      z = __builtin_amdgcn_mfma_f32_16x16x32_bf16(qa1, kb1, z, 0, 0, 0);
      sf[nt] = z;
    }
    // online softmax per row (row = quad*4+r, owned by quad's 16 lanes)
    unsigned short pb[4][4];
    #pragma unroll
    for (int r=0;r<4;++r){
      float rm = fmaxf(fmaxf(sf[0][r], sf[1][r]), fmaxf(sf[2][r], sf[3][r]));
      #pragma unroll
      for (int off=1; off<16; off<<=1) rm = fmaxf(rm, __shfl_xor(rm, off));
      float mnew = fmaxf(m_r[r], rm);
      float alpha = exp2f(m_r[r] - mnew);
      float rs = 0.f;
      #pragma unroll
      for (int nt=0;nt<4;++nt){
        unsigned short pbx = f2bf(exp2f(sf[nt][r] - mnew));
        pb[nt][r] = pbx;
        rs += bf2f(pbx);
      }
      #pragma unroll
      for (int off=1; off<16; off<<=1) rs += __shfl_xor(rs, off);
      l_r[r] = l_r[r]*alpha + rs;
      m_r[r] = mnew;
      #pragma unroll
      for (int nt=0;nt<4;++nt) o_acc[nt][r] *= alpha;
    }
    // P strip -> LDS (own strip only; same-wave ds dependency, no barrier)
    #pragma unroll
    for (int r=0;r<4;++r)
      #pragma unroll
      for (int nt=0;nt<4;++nt)
        p_lds[(w<<4)+(quad<<2)+r][(nt<<4)+l15] = pb[nt][r];
    // PV: O strip += P * V  (B from V natural [c][s] layout)
    short8 pa0 = *(const short8*)&p_lds[(w<<4)+l15][quad<<3];
    short8 pa1 = *(const short8*)&p_lds[(w<<4)+l15][32+(quad<<3)];
    #pragma unroll
    for (int nt=0;nt<4;++nt){
      short8 vb0 = *(const short8*)&v_lds[(nt<<4)+l15][quad<<3];
      short8 vb1 = *(const short8*)&v_lds[(nt<<4)+l15][32+(quad<<3)];
      f32x4 z = o_acc[nt];
      z = __builtin_amdgcn_mfma_f32_16x16x32_bf16(pa0, vb0, z, 0, 0, 0);
      z = __builtin_amdgcn_mfma_f32_16x16x32_bf16(pa1, vb1, z, 0, 0, 0);
      o_acc[nt] = z;
    }
  }
  // epilogue: normalize, transpose to [c][t] via q_lds, coalesced bf16 store
  float inv[4];
  #pragma unroll
  for (int r=0;r<4;++r) inv[r] = 1.f / l_r[r];
  #pragma unroll
  for (int nt=0;nt<4;++nt)
    #pragma unroll
    for (int r=0;r<4;++r)
      q_lds[(nt<<4)+l15][(w<<4)+(quad<<2)+r] = f2bf(o_acc[nt][r]*inv[r]);
  __syncthreads();
  unsigned short* ag = a + ((size_t)(bh>>2)*CCH + (bh&3)*64)*TT + t0;
  #pragma unroll
  for (int pass = 0; pass < 2; ++pass){
    int chunk = (pass<<8) + tid;
    int row = chunk >> 3, c8 = (chunk & 7) << 3;
    *(uint4*)(ag + (size_t)row*TT + c8) = *(const uint4*)&q_lds[row][c8];
  }
}

// ---------------- Kernel 5: proj GEMM + bias + residual (a is bf16) ---------
__global__ __launch_bounds__(256)
void proj_res(const float* __restrict__ w, const float* __restrict__ bias,
              const unsigned short* __restrict__ a, const float* __restrict__ x,
              float* __restrict__ out){
  __shared__ float wt[16][68];
  __shared__ float xt[16][68];
  int b = blockIdx.z;
  int o0 = blockIdx.y << 6;
  int t0 = blockIdx.x << 6;
  int tid = threadIdx.x;
  int tr = tid >> 4, ts = tid & 15;
  const unsigned short* ab = a + (size_t)b * CCH * TT;
  float acc[4][4] = {};
  for (int k0 = 0; k0 < 256; k0 += 16){
    __syncthreads();
    {
      int ol = tid >> 2, kq = (tid & 3) << 2;
      float4 u = *(const float4*)(w + (size_t)(o0 + ol) * 256 + k0 + kq);
      wt[kq+0][ol] = u.x; wt[kq+1][ol] = u.y;
      wt[kq+2][ol] = u.z; wt[kq+3][ol] = u.w;
    }
    {
      int kl = tid >> 4, j4 = (tid & 15) << 2;
      uint2 u = *(const uint2*)(ab + (size_t)(k0 + kl) * TT + t0 + j4);
      xt[kl][j4+0] = bf2f(u.x & 0xffffu);
      xt[kl][j4+1] = bf2f(u.x >> 16);
      xt[kl][j4+2] = bf2f(u.y & 0xffffu);
      xt[kl][j4+3] = bf2f(u.y >> 16);
    }
    __syncthreads();
    #pragma unroll
    for (int k = 0; k < 16; ++k){
      float4 a4 = *(const float4*)&wt[k][tr<<2];
      float4 b4 = *(const float4*)&xt[k][ts<<2];
      float av[4] = {a4.x,a4.y,a4.z,a4.w};
      float bv[4] = {b4.x,b4.y,b4.z,b4.w};
      #pragma unroll
      for (int i=0;i<4;++i)
        #pragma unroll
        for (int j=0;j<4;++j)
          acc[i][j] = fmaf(av[i], bv[j], acc[i][j]);
    }
  }
  #pragma unroll
  for (int i=0;i<4;++i){
    int o = o0 + (tr<<2) + i;
    float bsv = bias[o];
    size_t base = ((size_t)b * CCH + o) * TT + t0 + (ts<<2);
    float4 xr = *(const float4*)(x + base);
    float4 r;
    r.x = acc[i][0]+bsv+xr.x;
    r.y = acc[i][1]+bsv+xr.y;
    r.z = acc[i][2]+bsv+xr.z;
    r.w = acc[i][3]+bsv+xr.w;
    *(float4*)(out + base) = r;
  }
}

extern "C" void kernel_launch(void* const* d_in, const int* in_sizes, int n_in,
                              void* d_out, int out_size, void* d_ws, size_t ws_size,
                              hipStream_t stream){
  const float* x      = (const float*)d_in[0];
  const float* gn_w   = (const float*)d_in[1];
  const float* gn_b   = (const float*)d_in[2];
  const float* qkv_w  = (const float*)d_in[3];
  const float* qkv_b  = (const float*)d_in[4];
  const float* proj_w = (const float*)d_in[5];
  const float* proj_b = (const float*)d_in[6];
  float* out = (float*)d_out;

  // ws: stats(256 f32) | xn f32 16.8MB | qt,kt,v bf16 8.4MB each | a bf16 8.4MB
  float* stats = (float*)d_ws;
  float* xn    = stats + 256;
  unsigned short* qt = (unsigned short*)(xn + (size_t)4*CCH*TT);
  unsigned short* kt = qt + (size_t)16*TT*64;
  unsigned short* vv = kt + (size_t)16*TT*64;
  unsigned short* ab = vv + (size_t)16*64*TT;

  gn_stats<<<128, 256, 0, stream>>>(x, stats);
  gn_apply<<<4096, 256, 0, stream>>>(x, gn_w, gn_b, stats, xn);
  qkv_gemm<<<dim3(64, 12, 4), 256, 0, stream>>>(qkv_w, qkv_b, xn, qt, kt, vv);
  attn_mfma<<<1024, 256, 0, stream>>>(qt, kt, vv, ab);
  proj_res<<<dim3(64, 4, 4), 256, 0, stream>>>(proj_w, proj_b, ab, x, out);
}

// Round 4
// 313.697 us; speedup vs baseline: 3.9193x; 1.4754x over previous
//
#include <hip/hip_runtime.h>
#include <cstdint>
#include <cstddef>

#define TT 4096   // T = H*W
#define CCH 256   // C

typedef __attribute__((ext_vector_type(8))) short short8;
typedef __attribute__((ext_vector_type(4))) float f32x4;

__device__ __forceinline__ float bf2f(unsigned int u){
  union { unsigned int i; float f; } v; v.i = u << 16; return v.f;
}
__device__ __forceinline__ unsigned short f2bf(float f){      // RNE
  unsigned int x = __float_as_uint(f);
  x += 0x7fffu + ((x >> 16) & 1u);
  return (unsigned short)(x >> 16);
}
__device__ __forceinline__ unsigned short f2bf_t(float f){    // truncate (p in [0,1])
  return (unsigned short)(__float_as_uint(f) >> 16);
}

// ---------------- Kernel 0: f32 -> bf16 weight convert ----------------------
__global__ __launch_bounds__(256)
void wconv(const float* __restrict__ src, unsigned short* __restrict__ dst){
  int i = blockIdx.x * 256 + threadIdx.x;
  float4 u = *(const float4*)(src + (size_t)i * 4);
  ushort4 r; r.x = f2bf(u.x); r.y = f2bf(u.y); r.z = f2bf(u.z); r.w = f2bf(u.w);
  *(ushort4*)(dst + (size_t)i * 4) = r;
}

// ---------------- Kernel 1: GroupNorm partial sums (atomic) -----------------
// 512 blocks: sg = blockIdx>>2 (b*32+g), part = blockIdx&3 (t-quarter of 32768)
__global__ __launch_bounds__(256)
void gn_stats_part(const float* __restrict__ x, float* __restrict__ sums){
  int sg = blockIdx.x >> 2, part = blockIdx.x & 3;
  const float4* p = (const float4*)(x + (size_t)sg * 32768 + (size_t)part * 8192);
  int tid = threadIdx.x;
  float s = 0.f, sq = 0.f;
  #pragma unroll
  for (int it = 0; it < 8; ++it){
    float4 u = p[it * 256 + tid];
    s  += u.x + u.y + u.z + u.w;
    sq += u.x*u.x + u.y*u.y + u.z*u.z + u.w*u.w;
  }
  #pragma unroll
  for (int off = 32; off >= 1; off >>= 1){
    s  += __shfl_down(s, off);
    sq += __shfl_down(sq, off);
  }
  __shared__ float ls[4], lq[4];
  int w_ = tid >> 6, lane = tid & 63;
  if (lane == 0){ ls[w_] = s; lq[w_] = sq; }
  __syncthreads();
  if (tid == 0){
    atomicAdd(&sums[2*sg],   ls[0]+ls[1]+ls[2]+ls[3]);
    atomicAdd(&sums[2*sg+1], lq[0]+lq[1]+lq[2]+lq[3]);
  }
}

// ---------------- Kernel 2: GN apply + transpose -> xnT bf16 [b][t][256] ----
__global__ __launch_bounds__(256)
void gn_apply_t(const float* __restrict__ x, const float* __restrict__ gw,
                const float* __restrict__ gb, const float* __restrict__ sums,
                unsigned short* __restrict__ xnT){
  __shared__ unsigned short t_lds[64][72];   // [t_local][c_local]
  int tid = threadIdx.x;
  int t0 = blockIdx.x << 6, c0 = blockIdx.y << 6, b = blockIdx.z;
  int t4 = (tid & 15) << 2, cr = tid >> 4;
  #pragma unroll
  for (int pass = 0; pass < 4; ++pass){
    int cl = (pass << 4) + cr;
    int c = c0 + cl;
    int sg = (b << 5) | (c >> 3);
    float s = sums[2*sg], q = sums[2*sg+1];
    float mean = s * (1.f/32768.f);
    float var  = q * (1.f/32768.f) - mean*mean;
    float rstd = rsqrtf(var + 1e-5f);
    float sc = gw[c] * rstd;
    float sh = gb[c] - mean * sc;
    float4 u = *(const float4*)(x + ((size_t)(b*CCH + c))*TT + t0 + t4);
    t_lds[t4+0][cl] = f2bf(u.x*sc + sh);
    t_lds[t4+1][cl] = f2bf(u.y*sc + sh);
    t_lds[t4+2][cl] = f2bf(u.z*sc + sh);
    t_lds[t4+3][cl] = f2bf(u.w*sc + sh);
  }
  __syncthreads();
  #pragma unroll
  for (int pass = 0; pass < 2; ++pass){
    int chunk = (pass << 8) + tid;
    int row = chunk >> 3, c8 = (chunk & 7) << 3;
    *(uint4*)(xnT + ((size_t)b*TT + t0 + row)*256 + c0 + c8) = *(const uint4*)&t_lds[row][c8];
  }
}

// ---------------- Kernel 3: QKV GEMM (bf16 MFMA) ----------------------------
// D[o][t] = W[o,:]·xn[:,t]; grid (64 t-tiles, 12 o-tiles, 4 b), 4 waves x 16-o strips.
__global__ __launch_bounds__(256)
void qkv_mfma(const unsigned short* __restrict__ wb, const float* __restrict__ bias,
              const unsigned short* __restrict__ xnT,
              unsigned short* __restrict__ qT, unsigned short* __restrict__ kT,
              unsigned short* __restrict__ vO){
  __shared__ unsigned short x_lds[64][72];   // [t][c] per k-step; reused for epilogue
  int tid = threadIdx.x;
  int w = tid >> 6, lane = tid & 63, quad = lane >> 4, l15 = lane & 15;
  int t0 = blockIdx.x << 6, o0 = blockIdx.y << 6, b = blockIdx.z;
  const unsigned short* xb = xnT + (size_t)b * TT * 256;
  const unsigned short* wrow = wb + (size_t)(o0 + (w << 4) + l15) * 256;
  f32x4 acc[4];
  #pragma unroll
  for (int nt = 0; nt < 4; ++nt) acc[nt] = (f32x4){0.f,0.f,0.f,0.f};
  for (int ks = 0; ks < 4; ++ks){
    int k0 = ks << 6;
    __syncthreads();
    #pragma unroll
    for (int pass = 0; pass < 2; ++pass){
      int chunk = (pass << 8) + tid;
      int row = chunk >> 3, c8 = (chunk & 7) << 3;
      *(uint4*)&x_lds[row][c8] = *(const uint4*)(xb + (size_t)(t0 + row)*256 + k0 + c8);
    }
    __syncthreads();
    short8 wa0 = *(const short8*)(wrow + k0 + (quad << 3));
    short8 wa1 = *(const short8*)(wrow + k0 + 32 + (quad << 3));
    #pragma unroll
    for (int nt = 0; nt < 4; ++nt){
      short8 xb0 = *(const short8*)&x_lds[(nt << 4) + l15][quad << 3];
      short8 xb1 = *(const short8*)&x_lds[(nt << 4) + l15][32 + (quad << 3)];
      acc[nt] = __builtin_amdgcn_mfma_f32_16x16x32_bf16(wa0, xb0, acc[nt], 0, 0, 0);
      acc[nt] = __builtin_amdgcn_mfma_f32_16x16x32_bf16(wa1, xb1, acc[nt], 0, 0, 0);
    }
  }
  // epilogue
  int sec = blockIdx.y >> 2, h = blockIdx.y & 3, bh = (b << 2) | h;
  float bs[4];
  #pragma unroll
  for (int r = 0; r < 4; ++r) bs[r] = bias[o0 + (w << 4) + (quad << 2) + r];
  __syncthreads();   // all waves done reading x_lds
  if (sec < 2){      // q or k -> [bh][t][64] transposed via LDS
    float qsc = (sec == 0) ? 0.125f * 1.44269504f : 1.0f;
    #pragma unroll
    for (int nt = 0; nt < 4; ++nt){
      ushort4 pk;
      pk.x = f2bf((acc[nt][0] + bs[0]) * qsc);
      pk.y = f2bf((acc[nt][1] + bs[1]) * qsc);
      pk.z = f2bf((acc[nt][2] + bs[2]) * qsc);
      pk.w = f2bf((acc[nt][3] + bs[3]) * qsc);
      *(ushort4*)&x_lds[(nt << 4) + l15][(w << 4) + (quad << 2)] = pk;
    }
    __syncthreads();
    unsigned short* dst = (sec == 0) ? qT : kT;
    #pragma unroll
    for (int pass = 0; pass < 2; ++pass){
      int chunk = (pass << 8) + tid;
      int row = chunk >> 3, c8 = (chunk & 7) << 3;
      *(uint4*)(dst + ((size_t)bh*TT + t0 + row)*64 + c8) = *(const uint4*)&x_lds[row][c8];
    }
  } else {           // v -> [bh][64][T] natural
    #pragma unroll
    for (int nt = 0; nt < 4; ++nt)
      #pragma unroll
      for (int r = 0; r < 4; ++r)
        x_lds[(w << 4) + (quad << 2) + r][(nt << 4) + l15] = f2bf(acc[nt][r] + bs[r]);
    __syncthreads();
    #pragma unroll
    for (int pass = 0; pass < 2; ++pass){
      int chunk = (pass << 8) + tid;
      int row = chunk >> 3, c8 = (chunk & 7) << 3;
      *(uint4*)(vO + ((size_t)bh*64 + row)*TT + t0 + c8) = *(const uint4*)&x_lds[row][c8];
    }
  }
}

// ---------------- Kernel 4: flash attention, S^T orientation ----------------
// block = (bh, 128 queries); 4 waves x 32 q (2 tiles). 64 keys/iter.
// S^T = K·Q^T: D row = s (quad*4+r), col = t (l15)  -> softmax over s is
// 15 in-lane ops + 2 cross-quad shfls. P^T regs are column-consecutive in r
// -> vector ds_write_b64 into p_lds[t][s].
__global__ __launch_bounds__(256)
void attn2(const unsigned short* __restrict__ qT, const unsigned short* __restrict__ kT,
           const unsigned short* __restrict__ vO, unsigned short* __restrict__ aT){
  __shared__ __align__(16) unsigned short k_lds[64][72];    // [s][c]
  __shared__ __align__(16) unsigned short v_lds[64][72];    // [c][s]
  __shared__ __align__(16) unsigned short p_lds[128][72];   // [t][s]; reused as O[t][c]
  int tid = threadIdx.x;
  int w = tid >> 6, lane = tid & 63, quad = lane >> 4, l15 = lane & 15;
  int qt5 = blockIdx.x & 31, bh = blockIdx.x >> 5;
  int t0 = qt5 << 7;
  const unsigned short* qg = qT + (size_t)bh * TT * 64;
  const unsigned short* kg = kT + (size_t)bh * TT * 64;
  const unsigned short* vg = vO + (size_t)bh * 64 * TT;
  int tw = t0 + (w << 5);                 // wave's query base

  short8 qf[2][2];
  #pragma unroll
  for (int qt = 0; qt < 2; ++qt)
    #pragma unroll
    for (int hh = 0; hh < 2; ++hh)
      qf[qt][hh] = *(const short8*)(qg + (size_t)(tw + (qt << 4) + l15)*64 + (hh << 5) + (quad << 3));

  f32x4 o_acc[2][4];
  #pragma unroll
  for (int qt = 0; qt < 2; ++qt)
    #pragma unroll
    for (int ct = 0; ct < 4; ++ct) o_acc[qt][ct] = (f32x4){0.f,0.f,0.f,0.f};
  float m_[2] = {-1e30f, -1e30f}, l_[2] = {0.f, 0.f};

  for (int st = 0; st < 64; ++st){
    int s0 = st << 6;
    __syncthreads();                       // prev PV reads of k/v done
    #pragma unroll
    for (int pass = 0; pass < 2; ++pass){
      int chunk = (pass << 8) + tid;
      int row = chunk >> 3, c8 = (chunk & 7) << 3;
      *(uint4*)&k_lds[row][c8] = *(const uint4*)(kg + (size_t)(s0 + row)*64 + c8);
      *(uint4*)&v_lds[row][c8] = *(const uint4*)(vg + (size_t)row*TT + s0 + c8);
    }
    __syncthreads();
    // S^T tiles: [mt][qt]
    f32x4 sv[4][2];
    #pragma unroll
    for (int mt = 0; mt < 4; ++mt){
      short8 ka0 = *(const short8*)&k_lds[(mt << 4) + l15][quad << 3];
      short8 ka1 = *(const short8*)&k_lds[(mt << 4) + l15][32 + (quad << 3)];
      #pragma unroll
      for (int qt = 0; qt < 2; ++qt){
        f32x4 z = (f32x4){0.f,0.f,0.f,0.f};
        z = __builtin_amdgcn_mfma_f32_16x16x32_bf16(ka0, qf[qt][0], z, 0, 0, 0);
        z = __builtin_amdgcn_mfma_f32_16x16x32_bf16(ka1, qf[qt][1], z, 0, 0, 0);
        sv[mt][qt] = z;
      }
    }
    // online softmax per q-tile (col t = l15; s spans regs+quads)
    float alpha[2];
    #pragma unroll
    for (int qt = 0; qt < 2; ++qt){
      float rm = -1e30f;
      #pragma unroll
      for (int mt = 0; mt < 4; ++mt)
        #pragma unroll
        for (int r = 0; r < 4; ++r) rm = fmaxf(rm, sv[mt][qt][r]);
      rm = fmaxf(rm, __shfl_xor(rm, 16));
      rm = fmaxf(rm, __shfl_xor(rm, 32));
      float mnew = fmaxf(m_[qt], rm);
      alpha[qt] = exp2f(m_[qt] - mnew);
      float rs = 0.f;
      #pragma unroll
      for (int mt = 0; mt < 4; ++mt){
        float p0 = exp2f(sv[mt][qt][0] - mnew);
        float p1 = exp2f(sv[mt][qt][1] - mnew);
        float p2 = exp2f(sv[mt][qt][2] - mnew);
        float p3 = exp2f(sv[mt][qt][3] - mnew);
        rs += (p0 + p1) + (p2 + p3);
        ushort4 pk; pk.x = f2bf_t(p0); pk.y = f2bf_t(p1); pk.z = f2bf_t(p2); pk.w = f2bf_t(p3);
        *(ushort4*)&p_lds[(w << 5) + (qt << 4) + l15][(mt << 4) + (quad << 2)] = pk;
      }
      rs += __shfl_xor(rs, 16);
      rs += __shfl_xor(rs, 32);
      l_[qt] = l_[qt]*alpha[qt] + rs;
      m_[qt] = mnew;
    }
    // rescale O with per-row alpha (broadcast from lane quad*4+r)
    #pragma unroll
    for (int qt = 0; qt < 2; ++qt)
      #pragma unroll
      for (int r = 0; r < 4; ++r){
        float ar = __shfl(alpha[qt], (quad << 2) + r);
        #pragma unroll
        for (int ct = 0; ct < 4; ++ct) o_acc[qt][ct][r] *= ar;
      }
    // PV: O[t][c] += P[t][s]·V[c][s]^T
    short8 pa[2][2];
    #pragma unroll
    for (int qt = 0; qt < 2; ++qt){
      pa[qt][0] = *(const short8*)&p_lds[(w << 5) + (qt << 4) + l15][quad << 3];
      pa[qt][1] = *(const short8*)&p_lds[(w << 5) + (qt << 4) + l15][32 + (quad << 3)];
    }
    #pragma unroll
    for (int ct = 0; ct < 4; ++ct){
      short8 vb0 = *(const short8*)&v_lds[(ct << 4) + l15][quad << 3];
      short8 vb1 = *(const short8*)&v_lds[(ct << 4) + l15][32 + (quad << 3)];
      #pragma unroll
      for (int qt = 0; qt < 2; ++qt){
        o_acc[qt][ct] = __builtin_amdgcn_mfma_f32_16x16x32_bf16(pa[qt][0], vb0, o_acc[qt][ct], 0, 0, 0);
        o_acc[qt][ct] = __builtin_amdgcn_mfma_f32_16x16x32_bf16(pa[qt][1], vb1, o_acc[qt][ct], 0, 0, 0);
      }
    }
  }
  // epilogue: normalize, O -> p_lds[t][c], coalesced store to aT [b][t][256]
  #pragma unroll
  for (int qt = 0; qt < 2; ++qt)
    #pragma unroll
    for (int r = 0; r < 4; ++r){
      float lr = __shfl(l_[qt], (quad << 2) + r);
      float ir = 1.f / lr;
      #pragma unroll
      for (int ct = 0; ct < 4; ++ct)
        p_lds[(w << 5) + (qt << 4) + (quad << 2) + r][(ct << 4) + l15] = f2bf(o_acc[qt][ct][r] * ir);
    }
  __syncthreads();
  size_t abase = ((size_t)(bh >> 2)*TT + t0)*256 + (size_t)(bh & 3)*64;
  #pragma unroll
  for (int pass = 0; pass < 4; ++pass){
    int chunk = (pass << 8) + tid;
    int row = chunk >> 3, c8 = (chunk & 7) << 3;
    *(uint4*)(aT + abase + (size_t)row*256 + c8) = *(const uint4*)&p_lds[row][c8];
  }
}

// ---------------- Kernel 5: proj GEMM (bf16 MFMA) + bias + residual ---------
__global__ __launch_bounds__(256)
void proj_mfma(const unsigned short* __restrict__ wb, const float* __restrict__ bias,
               const unsigned short* __restrict__ aT, const float* __restrict__ x,
               float* __restrict__ out){
  __shared__ unsigned short x_lds[64][72];
  int tid = threadIdx.x;
  int w = tid >> 6, lane = tid & 63, quad = lane >> 4, l15 = lane & 15;
  int t0 = blockIdx.x << 6, o0 = blockIdx.y << 6, b = blockIdx.z;
  const unsigned short* xb = aT + (size_t)b * TT * 256;
  const unsigned short* wrow = wb + (size_t)(o0 + (w << 4) + l15) * 256;
  f32x4 acc[4];
  #pragma unroll
  for (int nt = 0; nt < 4; ++nt) acc[nt] = (f32x4){0.f,0.f,0.f,0.f};
  for (int ks = 0; ks < 4; ++ks){
    int k0 = ks << 6;
    __syncthreads();
    #pragma unroll
    for (int pass = 0; pass < 2; ++pass){
      int chunk = (pass << 8) + tid;
      int row = chunk >> 3, c8 = (chunk & 7) << 3;
      *(uint4*)&x_lds[row][c8] = *(const uint4*)(xb + (size_t)(t0 + row)*256 + k0 + c8);
    }
    __syncthreads();
    short8 wa0 = *(const short8*)(wrow + k0 + (quad << 3));
    short8 wa1 = *(const short8*)(wrow + k0 + 32 + (quad << 3));
    #pragma unroll
    for (int nt = 0; nt < 4; ++nt){
      short8 xb0 = *(const short8*)&x_lds[(nt << 4) + l15][quad << 3];
      short8 xb1 = *(const short8*)&x_lds[(nt << 4) + l15][32 + (quad << 3)];
      acc[nt] = __builtin_amdgcn_mfma_f32_16x16x32_bf16(wa0, xb0, acc[nt], 0, 0, 0);
      acc[nt] = __builtin_amdgcn_mfma_f32_16x16x32_bf16(wa1, xb1, acc[nt], 0, 0, 0);
    }
  }
  #pragma unroll
  for (int r = 0; r < 4; ++r){
    int o = o0 + (w << 4) + (quad << 2) + r;
    float bsv = bias[o];
    #pragma unroll
    for (int nt = 0; nt < 4; ++nt){
      size_t idx = ((size_t)(b*CCH + o))*TT + t0 + (nt << 4) + l15;
      out[idx] = acc[nt][r] + bsv + x[idx];
    }
  }
}

extern "C" void kernel_launch(void* const* d_in, const int* in_sizes, int n_in,
                              void* d_out, int out_size, void* d_ws, size_t ws_size,
                              hipStream_t stream){
  const float* x      = (const float*)d_in[0];
  const float* gn_w   = (const float*)d_in[1];
  const float* gn_b   = (const float*)d_in[2];
  const float* qkv_w  = (const float*)d_in[3];
  const float* qkv_b  = (const float*)d_in[4];
  const float* proj_w = (const float*)d_in[5];
  const float* proj_b = (const float*)d_in[6];
  float* out = (float*)d_out;

  float* sums = (float*)d_ws;                                  // 256 used, pad 1024
  unsigned short* wq_bf = (unsigned short*)(sums + 1024);      // 768*256
  unsigned short* wp_bf = wq_bf + (size_t)768*256;             // 256*256
  unsigned short* xnT   = wp_bf + (size_t)256*256;             // [4][4096][256]
  unsigned short* qT    = xnT + (size_t)4*TT*256;              // [16][4096][64]
  unsigned short* kT    = qT  + (size_t)16*TT*64;
  unsigned short* vO    = kT  + (size_t)16*TT*64;              // [16][64][4096]
  unsigned short* aT    = vO  + (size_t)16*64*TT;              // [4][4096][256]

  hipMemsetAsync(sums, 0, 1024*sizeof(float), stream);
  wconv<<<192, 256, 0, stream>>>(qkv_w, wq_bf);
  wconv<<<64, 256, 0, stream>>>(proj_w, wp_bf);
  gn_stats_part<<<512, 256, 0, stream>>>(x, sums);
  gn_apply_t<<<dim3(64, 4, 4), 256, 0, stream>>>(x, gn_w, gn_b, sums, xnT);
  qkv_mfma<<<dim3(64, 12, 4), 256, 0, stream>>>(wq_bf, qkv_b, xnT, qT, kT, vO);
  attn2<<<512, 256, 0, stream>>>(qT, kT, vO, aT);
  proj_mfma<<<dim3(64, 4, 4), 256, 0, stream>>>(wp_bf, proj_b, aT, x, out);
}